// Round 1
// baseline (3022.889 us; speedup 1.0000x reference)
//
#include <hip/hip_runtime.h>

#define NSTATES 256
#define SEQ 1024
#define NSYM 100

// ---------- transpose W[a][i][j] -> WT[a][j][i] (once per launch, ~26 MB) ----------
__global__ __launch_bounds__(256) void transpose_k(const float* __restrict__ W,
                                                   float* __restrict__ WT) {
    __shared__ float tile[32][33];
    int a = blockIdx.y;
    int t = blockIdx.x;                 // 64 tiles of 32x32 per matrix
    int tr = (t >> 3) << 5;             // tile row origin
    int tc = (t & 7) << 5;              // tile col origin
    const float* src = W + (size_t)a * (NSTATES * NSTATES);
    float* dst = WT + (size_t)a * (NSTATES * NSTATES);
    int x = threadIdx.x & 31;
    int y4 = threadIdx.x >> 5;          // 0..7
#pragma unroll
    for (int yy = 0; yy < 4; yy++) {
        int y = y4 * 4 + yy;
        tile[y][x] = src[(size_t)(tr + y) * NSTATES + tc + x];
    }
    __syncthreads();
#pragma unroll
    for (int yy = 0; yy < 4; yy++) {
        int y = y4 * 4 + yy;
        dst[(size_t)(tc + y) * NSTATES + tr + x] = tile[x][y];
    }
}

// ---------- main chain kernel, transposed-W path ----------
// grid = B, block = 1024 (16 waves). Wave w owns j in [16w,16w+16); lane owns
// outputs i = 4*lane..4*lane+3 (float4 along i, coalesced in WT).
__global__ __launch_bounds__(1024) void pann_fwd(const int* __restrict__ xs,
                                                 const int* __restrict__ lengths,
                                                 const float* __restrict__ WT,
                                                 const float* __restrict__ lin_w,
                                                 const float* __restrict__ lin_b,
                                                 float* __restrict__ out) {
    __shared__ float h[NSTATES];
    __shared__ float partial[16][NSTATES];
    __shared__ int xrow[SEQ];

    int b = blockIdx.x;
    int tid = threadIdx.x;
    int w = tid >> 6;
    int lane = tid & 63;

    xrow[tid] = xs[(size_t)b * SEQ + tid];
    if (tid < NSTATES) h[tid] = (tid == 0) ? 1.0f : 0.0f;
    int len = lengths[b];
    __syncthreads();

    int jbase = w << 4;
    for (int t = 0; t < len; t++) {
        int x = xrow[t];
        const float4* wp = (const float4*)(WT + (size_t)x * (NSTATES * NSTATES));
        float ax = 0.f, ay = 0.f, az = 0.f, aw = 0.f;
#pragma unroll
        for (int jj = 0; jj < 16; jj++) {
            int j = jbase + jj;
            float4 wv = wp[j * 64 + lane];   // WT row j, 16B per lane, coalesced
            float hj = h[j];                 // LDS broadcast
            ax = fmaf(wv.x, hj, ax);
            ay = fmaf(wv.y, hj, ay);
            az = fmaf(wv.z, hj, az);
            aw = fmaf(wv.w, hj, aw);
        }
        float4* pp = (float4*)&partial[w][lane << 2];
        *pp = make_float4(ax, ay, az, aw);
        __syncthreads();
        if (tid < NSTATES) {
            float s = 0.f;
#pragma unroll
            for (int ww = 0; ww < 16; ww++) s += partial[ww][tid];
            h[tid] = s;
        }
        __syncthreads();
    }

    // ---- head: out[b,k] = lin_w[k,:] @ h + lin_b[k] ----
    if (tid < NSTATES) {
        float hv = h[tid];
        partial[0][tid] = hv * lin_w[tid];
        partial[1][tid] = hv * lin_w[NSTATES + tid];
    }
    __syncthreads();
    for (int s = 128; s > 0; s >>= 1) {
        if (tid < s) {
            partial[0][tid] += partial[0][tid + s];
            partial[1][tid] += partial[1][tid + s];
        }
        __syncthreads();
    }
    if (tid == 0) {
        out[b * 2 + 0] = partial[0][0] + lin_b[0];
        out[b * 2 + 1] = partial[1][0] + lin_b[1];
    }
}

// ---------- fallback: no-transpose path (if d_ws too small) ----------
__global__ __launch_bounds__(1024) void pann_fwd_nt(const int* __restrict__ xs,
                                                    const int* __restrict__ lengths,
                                                    const float* __restrict__ W,
                                                    const float* __restrict__ lin_w,
                                                    const float* __restrict__ lin_b,
                                                    float* __restrict__ out) {
    __shared__ float hbuf[2][NSTATES];
    __shared__ float opart[2][NSTATES];
    __shared__ int xrow[SEQ];

    int b = blockIdx.x;
    int tid = threadIdx.x;
    int w = tid >> 6;
    int lane = tid & 63;

    xrow[tid] = xs[(size_t)b * SEQ + tid];
    if (tid < NSTATES) hbuf[0][tid] = (tid == 0) ? 1.0f : 0.0f;
    int len = lengths[b];
    __syncthreads();

    int cur = 0;
    for (int t = 0; t < len; t++) {
        int x = xrow[t];
        const float4* wp = (const float4*)(W + (size_t)x * (NSTATES * NSTATES));
        float4 hv = *(const float4*)&hbuf[cur][lane << 2];
#pragma unroll
        for (int ii = 0; ii < 4; ii++) {
            int i = (w << 4) + ii * 4;     // 16 rows per wave, 4 at a time
#pragma unroll
            for (int k = 0; k < 4; k++) {
                int row = i + k;
                float4 wv = wp[row * 64 + lane];   // W row, along j, coalesced
                float p = wv.x * hv.x + wv.y * hv.y + wv.z * hv.z + wv.w * hv.w;
#pragma unroll
                for (int off = 32; off > 0; off >>= 1) p += __shfl_down(p, off);
                if (lane == 0) hbuf[cur ^ 1][row] = p;
            }
        }
        __syncthreads();
        cur ^= 1;
    }

    if (tid < NSTATES) {
        float hv = hbuf[cur][tid];
        opart[0][tid] = hv * lin_w[tid];
        opart[1][tid] = hv * lin_w[NSTATES + tid];
    }
    __syncthreads();
    for (int s = 128; s > 0; s >>= 1) {
        if (tid < s) {
            opart[0][tid] += opart[0][tid + s];
            opart[1][tid] += opart[1][tid + s];
        }
        __syncthreads();
    }
    if (tid == 0) {
        out[b * 2 + 0] = opart[0][0] + lin_b[0];
        out[b * 2 + 1] = opart[1][0] + lin_b[1];
    }
}

extern "C" void kernel_launch(void* const* d_in, const int* in_sizes, int n_in,
                              void* d_out, int out_size, void* d_ws, size_t ws_size,
                              hipStream_t stream) {
    const int* xs = (const int*)d_in[0];
    const int* lengths = (const int*)d_in[1];
    const float* W = (const float*)d_in[2];
    const float* lin_w = (const float*)d_in[3];
    const float* lin_b = (const float*)d_in[4];
    float* out = (float*)d_out;

    int B = in_sizes[0] / SEQ;
    size_t wbytes = (size_t)NSYM * NSTATES * NSTATES * sizeof(float);

    if (ws_size >= wbytes) {
        float* WT = (float*)d_ws;
        dim3 tg(64, NSYM);
        transpose_k<<<tg, 256, 0, stream>>>(W, WT);
        pann_fwd<<<B, 1024, 0, stream>>>(xs, lengths, WT, lin_w, lin_b, out);
    } else {
        pann_fwd_nt<<<B, 1024, 0, stream>>>(xs, lengths, W, lin_w, lin_b, out);
    }
}

// Round 4
// 2147.259 us; speedup vs baseline: 1.4078x; 1.4078x over previous
//
#include <hip/hip_runtime.h>
#include <hip/hip_fp16.h>

#define NSTATES 256
#define SEQ 1024
#define NSYM 100

// ---------- prep: W[a][i][j] f32 -> WT[a][j][i] fp16 (13 MB, once) ----------
__global__ __launch_bounds__(256) void prep_k(const float* __restrict__ W,
                                              __half* __restrict__ WT) {
    __shared__ float tile[32][33];
    int a = blockIdx.y;
    int t = blockIdx.x;                 // 64 tiles of 32x32 per matrix
    int tr = (t >> 3) << 5;
    int tc = (t & 7) << 5;
    const float* src = W + (size_t)a * (NSTATES * NSTATES);
    __half* dst = WT + (size_t)a * (NSTATES * NSTATES);
    int x = threadIdx.x & 31;
    int y4 = threadIdx.x >> 5;
#pragma unroll
    for (int yy = 0; yy < 4; yy++) {
        int y = y4 * 4 + yy;
        tile[y][x] = src[(size_t)(tr + y) * NSTATES + tc + x];
    }
    __syncthreads();
#pragma unroll
    for (int yy = 0; yy < 4; yy++) {
        int y = y4 * 4 + yy;
        dst[(size_t)(tc + y) * NSTATES + tr + x] = __float2half(tile[x][y]);
    }
}

// ---------- main chain kernel: fp16 weights, f32 math, register prefetch ----------
// grid = B, block = 1024 (16 waves). Wave w owns j in [16w,16w+16); lane owns
// outputs i = 4*lane..4*lane+3. Loads for step t+1 are issued into the idle
// register buffer BEFORE step t's compute/barriers, so the load pipe never drains.
__global__ __launch_bounds__(1024) void pann_fwd_h(const int* __restrict__ xs,
                                                   const int* __restrict__ lengths,
                                                   const __half* __restrict__ WT,
                                                   const float* __restrict__ lin_w,
                                                   const float* __restrict__ lin_b,
                                                   float* __restrict__ out) {
    __shared__ float h[NSTATES];
    __shared__ float partial[16][NSTATES];
    __shared__ int xrow[SEQ];

    int b = blockIdx.x;
    int tid = threadIdx.x;
    int w = tid >> 6;
    int lane = tid & 63;

    xrow[tid] = xs[(size_t)b * SEQ + tid];
    if (tid < NSTATES) h[tid] = (tid == 0) ? 1.0f : 0.0f;
    int len = lengths[b];
    __syncthreads();

    int jbase = w << 4;
    // WT viewed as ushort4 (4 halves, 8B): row j has 64 ushort4; matrix = 16384.
    const ushort4* W4 = (const ushort4*)WT;
    const ushort4* wl = W4 + jbase * 64 + lane;   // per-lane base within a matrix

    ushort4 Ra[16], Rb[16];
    {
        int x0 = __builtin_amdgcn_readfirstlane(xrow[0]);
        const ushort4* p = wl + (size_t)x0 * 16384;
#pragma unroll
        for (int jj = 0; jj < 16; jj++) Ra[jj] = p[jj * 64];
    }

    int t = 0;
#define PHASE(RCUR, RNXT)                                                     \
    {                                                                         \
        int tn = t + 1; if (tn >= len) tn = t;                                \
        int xn = __builtin_amdgcn_readfirstlane(xrow[tn]);                    \
        const ushort4* pn = wl + (size_t)xn * 16384;                          \
        _Pragma("unroll")                                                     \
        for (int jj = 0; jj < 16; jj++) RNXT[jj] = pn[jj * 64];               \
        float ax = 0.f, ay = 0.f, az = 0.f, aw = 0.f;                         \
        _Pragma("unroll")                                                     \
        for (int jj = 0; jj < 16; jj++) {                                     \
            float hj = h[jbase + jj];                                         \
            float2 f0 = __half22float2(*(const __half2*)&RCUR[jj].x);         \
            float2 f1 = __half22float2(*(const __half2*)&RCUR[jj].z);         \
            ax = fmaf(f0.x, hj, ax);                                          \
            ay = fmaf(f0.y, hj, ay);                                          \
            az = fmaf(f1.x, hj, az);                                          \
            aw = fmaf(f1.y, hj, aw);                                          \
        }                                                                     \
        *(float4*)&partial[w][lane << 2] = make_float4(ax, ay, az, aw);       \
        __syncthreads();                                                      \
        if (tid < NSTATES) {                                                  \
            float s = 0.f;                                                    \
            _Pragma("unroll")                                                 \
            for (int ww = 0; ww < 16; ww++) s += partial[ww][tid];            \
            h[tid] = s;                                                       \
        }                                                                     \
        __syncthreads();                                                      \
        t++;                                                                  \
    }

    while (t < len) {
        PHASE(Ra, Rb);
        if (t >= len) break;
        PHASE(Rb, Ra);
    }
#undef PHASE

    // ---- head: out[b,k] = lin_w[k,:] @ h + lin_b[k] ----
    if (tid < NSTATES) {
        float hv = h[tid];
        partial[0][tid] = hv * lin_w[tid];
        partial[1][tid] = hv * lin_w[NSTATES + tid];
    }
    __syncthreads();
    for (int s = 128; s > 0; s >>= 1) {
        if (tid < s) {
            partial[0][tid] += partial[0][tid + s];
            partial[1][tid] += partial[1][tid + s];
        }
        __syncthreads();
    }
    if (tid == 0) {
        out[b * 2 + 0] = partial[0][0] + lin_b[0];
        out[b * 2 + 1] = partial[1][0] + lin_b[1];
    }
}

// ---------- fallback: f32 no-transpose path (only if d_ws too small) ----------
__global__ __launch_bounds__(1024) void pann_fwd_nt(const int* __restrict__ xs,
                                                    const int* __restrict__ lengths,
                                                    const float* __restrict__ W,
                                                    const float* __restrict__ lin_w,
                                                    const float* __restrict__ lin_b,
                                                    float* __restrict__ out) {
    __shared__ float hbuf[2][NSTATES];
    __shared__ float opart[2][NSTATES];
    __shared__ int xrow[SEQ];

    int b = blockIdx.x;
    int tid = threadIdx.x;
    int w = tid >> 6;
    int lane = tid & 63;

    xrow[tid] = xs[(size_t)b * SEQ + tid];
    if (tid < NSTATES) hbuf[0][tid] = (tid == 0) ? 1.0f : 0.0f;
    int len = lengths[b];
    __syncthreads();

    int cur = 0;
    for (int t = 0; t < len; t++) {
        int x = xrow[t];
        const float4* wp = (const float4*)(W + (size_t)x * (NSTATES * NSTATES));
        float4 hv = *(const float4*)&hbuf[cur][lane << 2];
#pragma unroll
        for (int ii = 0; ii < 4; ii++) {
            int i = (w << 4) + ii * 4;
#pragma unroll
            for (int k = 0; k < 4; k++) {
                int row = i + k;
                float4 wv = wp[row * 64 + lane];
                float p = wv.x * hv.x + wv.y * hv.y + wv.z * hv.z + wv.w * hv.w;
#pragma unroll
                for (int off = 32; off > 0; off >>= 1) p += __shfl_down(p, off);
                if (lane == 0) hbuf[cur ^ 1][row] = p;
            }
        }
        __syncthreads();
        cur ^= 1;
    }

    if (tid < NSTATES) {
        float hv = hbuf[cur][tid];
        opart[0][tid] = hv * lin_w[tid];
        opart[1][tid] = hv * lin_w[NSTATES + tid];
    }
    __syncthreads();
    for (int s = 128; s > 0; s >>= 1) {
        if (tid < s) {
            opart[0][tid] += opart[0][tid + s];
            opart[1][tid] += opart[1][tid + s];
        }
        __syncthreads();
    }
    if (tid == 0) {
        out[b * 2 + 0] = opart[0][0] + lin_b[0];
        out[b * 2 + 1] = opart[1][0] + lin_b[1];
    }
}

extern "C" void kernel_launch(void* const* d_in, const int* in_sizes, int n_in,
                              void* d_out, int out_size, void* d_ws, size_t ws_size,
                              hipStream_t stream) {
    const int* xs = (const int*)d_in[0];
    const int* lengths = (const int*)d_in[1];
    const float* W = (const float*)d_in[2];
    const float* lin_w = (const float*)d_in[3];
    const float* lin_b = (const float*)d_in[4];
    float* out = (float*)d_out;

    int B = in_sizes[0] / SEQ;
    size_t wbytes = (size_t)NSYM * NSTATES * NSTATES * sizeof(__half);

    if (ws_size >= wbytes) {
        __half* WT = (__half*)d_ws;
        dim3 tg(64, NSYM);
        prep_k<<<tg, 256, 0, stream>>>(W, WT);
        pann_fwd_h<<<B, 1024, 0, stream>>>(xs, lengths, WT, lin_w, lin_b, out);
    } else {
        pann_fwd_nt<<<B, 1024, 0, stream>>>(xs, lengths, W, lin_w, lin_b, out);
    }
}